// Round 8
// baseline (10167.809 us; speedup 1.0000x reference)
//
#include <hip/hip_runtime.h>

#define P_ 128
#define T_ 2048
#define D_ 128
#define H_ 64
#define G_ 192
#define OUT_ 24

typedef float v2f __attribute__((ext_vector_type(2)));

__device__ __forceinline__ float rcpf_(float x){ return __builtin_amdgcn_rcpf(x); }
__device__ __forceinline__ float sigmoidf_(float x){ return rcpf_(1.0f + __expf(-x)); }
// tanh(x) = 1 - 2/(e^{2x}+1): branch-free, saturates correctly at +/-inf.
__device__ __forceinline__ float tanhf_(float x){
  float e = __expf(2.0f*x);
  return 1.0f - 2.0f*rcpf_(e + 1.0f);
}

// ---------------- Phase 1: x_proj[p, tl, g] = sum_d z[p,t0+tl,d]*w_ih[p,g,d] + b_ih[p,g]
__global__ __launch_bounds__(256) void xproj_kernel(
    const float* __restrict__ z, const float* __restrict__ w_ih,
    const float* __restrict__ b_ih, float* __restrict__ xp,
    int t0, int tcLen)
{
  __shared__ float zl[64*132];
  const int p = blockIdx.y;
  const int tBase = blockIdx.x*64;
  const int tid = threadIdx.x;
  const float* zg = z + ((size_t)p*T_ + (size_t)(t0 + tBase))*D_;
  #pragma unroll
  for (int i=0;i<8;i++){
    int idx = tid + i*256;
    int r = idx >> 5, c = idx & 31;
    *(float4*)(zl + r*132 + c*4) = *(const float4*)(zg + (size_t)r*D_ + c*4);
  }
  __syncthreads();

  const int tg = tid & 15, ng = tid >> 4;
  const int n0 = ng*12, tr = tg*4;
  const float* wg = w_ih + (size_t)p*G_*D_;
  float acc[4][12];
  #pragma unroll
  for (int j=0;j<12;j++){
    float b = b_ih[p*G_ + n0 + j];
    #pragma unroll
    for (int i=0;i<4;i++) acc[i][j] = b;
  }
  #pragma unroll 4
  for (int k=0;k<D_;k+=4){
    float4 x4[4];
    #pragma unroll
    for (int i=0;i<4;i++) x4[i] = *(const float4*)(zl + (tr+i)*132 + k);
    #pragma unroll
    for (int j=0;j<12;j++){
      float4 w4 = *(const float4*)(wg + (size_t)(n0+j)*D_ + k);
      #pragma unroll
      for (int i=0;i<4;i++)
        acc[i][j] = fmaf(x4[i].x,w4.x, fmaf(x4[i].y,w4.y, fmaf(x4[i].z,w4.z, fmaf(x4[i].w,w4.w, acc[i][j]))));
    }
  }
  float* orow = xp + ((size_t)p*tcLen + tBase)*G_;
  #pragma unroll
  for (int i=0;i<4;i++){
    #pragma unroll
    for (int j3=0;j3<3;j3++){
      float4 v = make_float4(acc[i][j3*4+0],acc[i][j3*4+1],acc[i][j3*4+2],acc[i][j3*4+3]);
      *(float4*)(orow + (size_t)(tr+i)*G_ + n0 + j3*4) = v;
    }
  }
}

// ---------------- Phase 2: GRU recurrence (6 waves, gate x half-row — R7 structure,
// unchanged) + FUSED MLP riding in the per-step latency windows.
// MLP schedule: wave w = t%6 snapshots h(t) and computes that timestep's full
// 64->128->64->32->24 MLP over the next 6 steps, one ~64-FMA segment per step,
// placed right after the barrier (post-barrier gx-read + tail latency window).
// Weights are read from GLOBAL (L1/L2-resident; per-seg working set <= 32KB).
// Layer exchanges use wave-PRIVATE LDS buffers -> no extra barriers anywhere.
// This deletes the separate mlp kernel and the 67MB hs write + 67MB read.
__global__ __launch_bounds__(384, 1) void gru_kernel(
    const float* __restrict__ xp, const float* __restrict__ w_hh,
    const float* __restrict__ b_hh,
    const float* __restrict__ w1, const float* __restrict__ b1,
    const float* __restrict__ w2, const float* __restrict__ b2,
    const float* __restrict__ w3, const float* __restrict__ b3,
    const float* __restrict__ w4, const float* __restrict__ b4,
    float* __restrict__ out, float* __restrict__ hstate,
    int t0, int tcLen)
{
  __shared__ __align__(16) float hbc[6][64];   // per-wave private h broadcast
  __shared__ __align__(16) float gxp[2][6][64];// partial-dot exchange, dbuf
  __shared__ __align__(16) float hsnap[6][64]; // per-wave mlp input snapshot
  __shared__ __align__(16) float o1[6][128];   // per-wave mlp layer outputs
  __shared__ __align__(16) float o2[6][64];
  __shared__ __align__(16) float o3[6][32];

  const int p   = blockIdx.x;
  const int tid = threadIdx.x;
  const int w   = tid >> 6;                    // wave 0..5
  const int g   = w >> 1;                      // gate 0=r,1=z,2=n
  const int hfr = w & 1;                       // half of the recurrence dot
  const int l   = tid & 63;

  // Recurrence weights: half gate-row, 16 v2f = 32 VGPRs.
  v2f wg2[16];
  {
    const float* Wg = w_hh + ((size_t)p*G_ + 64*g + l)*H_ + 32*hfr;
    #pragma unroll
    for (int i=0;i<8;i++){
      float4 a = *(const float4*)(Wg + 4*i);
      wg2[2*i]   = v2f{a.x, a.y};
      wg2[2*i+1] = v2f{a.z, a.w};
    }
  }
  const float br = b_hh[p*G_ + l];
  const float bz = b_hh[p*G_ + 64 + l];
  const float bn = b_hh[p*G_ + 128 + l];

  // MLP pointers + per-lane bias preloads (one-time).
  const float* W1 = w1 + (size_t)p*128*64;
  const float* W2 = w2 + (size_t)p*64*128;
  const float* W3 = w3 + (size_t)p*32*64;
  const float* W4 = w4 + (size_t)p*24*32;
  const float bb1a = b1[p*128 + l];
  const float bb1b = b1[p*128 + 64 + l];
  const float bb2  = b2[p*64 + l];
  const float bb3  = b3[p*32 + (l & 31)];
  const int   r4_  = l >> 1;
  const int   r4c_ = r4_ < 24 ? r4_ : 23;
  const float bb4  = b4[p*24 + r4c_];

  float h = 0.0f;
  if (t0 != 0) h = hstate[p*H_ + l];
  hbc[w][l] = h;                               // seed own broadcast buffer

  const float* xrow = xp + (size_t)p*tcLen*G_;

  // 2-deep x prefetch (A=even steps, B=odd steps).
  float xrA = xrow[l], xzA = xrow[64+l], xnA = xrow[128+l];
  const float* x1 = xrow + G_;
  float xrB = x1[l], xzB = x1[64+l], xnB = x1[128+l];

  // MLP state.
  int myT = -1, seg = 6;
  float a0 = 0.f, a1 = 0.f, c0 = 0.f;

  auto dot4 = [](float4 a, float4 b, float acc){
    return fmaf(a.x,b.x, fmaf(a.y,b.y, fmaf(a.z,b.z, fmaf(a.w,b.w, acc))));
  };

  auto runSeg = [&](int s){
    switch (s){
      case 0: {                                // L1 rows l & 64+l, k=0..31
        a0 = 0.f; a1 = 0.f;
        #pragma unroll
        for (int k4=0;k4<8;k4++){
          float4 hv = *(const float4*)(&hsnap[w][k4*4]);
          float4 wA = *(const float4*)(W1 + (size_t)l*64 + k4*4);
          float4 wB = *(const float4*)(W1 + (size_t)(64+l)*64 + k4*4);
          a0 = dot4(wA,hv,a0); a1 = dot4(wB,hv,a1);
        }
      } break;
      case 1: {                                // L1 k=32..63 + relu + store
        #pragma unroll
        for (int k4=8;k4<16;k4++){
          float4 hv = *(const float4*)(&hsnap[w][k4*4]);
          float4 wA = *(const float4*)(W1 + (size_t)l*64 + k4*4);
          float4 wB = *(const float4*)(W1 + (size_t)(64+l)*64 + k4*4);
          a0 = dot4(wA,hv,a0); a1 = dot4(wB,hv,a1);
        }
        o1[w][l]    = fmaxf(a0 + bb1a, 0.f);
        o1[w][64+l] = fmaxf(a1 + bb1b, 0.f);
      } break;
      case 2: {                                // L2 row l, k=0..63
        c0 = 0.f;
        #pragma unroll
        for (int k4=0;k4<16;k4++){
          float4 xv = *(const float4*)(&o1[w][k4*4]);
          float4 wv = *(const float4*)(W2 + (size_t)l*128 + k4*4);
          c0 = dot4(wv,xv,c0);
        }
      } break;
      case 3: {                                // L2 k=64..127 + relu + store
        #pragma unroll
        for (int k4=16;k4<32;k4++){
          float4 xv = *(const float4*)(&o1[w][k4*4]);
          float4 wv = *(const float4*)(W2 + (size_t)l*128 + k4*4);
          c0 = dot4(wv,xv,c0);
        }
        o2[w][l] = fmaxf(c0 + bb2, 0.f);
      } break;
      case 4: {                                // L3: row=l&31, k-half=l>>5
        const int r3 = l & 31, hf3 = l >> 5;
        float d0 = 0.f;
        #pragma unroll
        for (int k4=0;k4<8;k4++){
          float4 xv = *(const float4*)(&o2[w][hf3*32 + k4*4]);
          float4 wv = *(const float4*)(W3 + (size_t)r3*64 + hf3*32 + k4*4);
          d0 = dot4(wv,xv,d0);
        }
        d0 += __shfl_xor(d0, 32);
        if (l < 32) o3[w][l] = fmaxf(d0 + bb3, 0.f);
      } break;
      case 5: {                                // L4: row=l>>1, k-half=l&1 + store out
        const int hf4 = l & 1;
        float e0 = 0.f;
        #pragma unroll
        for (int k4=0;k4<4;k4++){
          float4 xv = *(const float4*)(&o3[w][hf4*16 + k4*4]);
          float4 wv = *(const float4*)(W4 + (size_t)r4c_*32 + hf4*16 + k4*4);
          e0 = dot4(wv,xv,e0);
        }
        e0 += __shfl_xor(e0, 1);
        if (r4_ < 24 && hf4 == 0)
          out[((size_t)p*T_ + (size_t)(t0 + myT))*OUT_ + r4_] = e0 + bb4;
      } break;
    }
  };

  auto step = [&](float& xr, float& xz, float& xn, int tl){
    const int b = tl & 1;
    // h-half broadcast: 8 x ds_read_b128, all lanes same address.
    float4 h4[8];
    #pragma unroll
    for (int j=0;j<8;j++) h4[j] = *(const float4*)(&hbc[w][32*hfr + 4*j]);
    __builtin_amdgcn_sched_barrier(0);         // pin reads before FMAs

    v2f A0 = v2f{0.0f, 0.0f}, A1 = v2f{0.0f, 0.0f};
    #pragma unroll
    for (int j=0;j<4;j++){
      v2f hA = v2f{h4[2*j].x,   h4[2*j].y};
      v2f hB = v2f{h4[2*j].z,   h4[2*j].w};
      v2f hC = v2f{h4[2*j+1].x, h4[2*j+1].y};
      v2f hD = v2f{h4[2*j+1].z, h4[2*j+1].w};
      A0 = __builtin_elementwise_fma(wg2[4*j],   hA, A0);
      A1 = __builtin_elementwise_fma(wg2[4*j+1], hB, A1);
      A0 = __builtin_elementwise_fma(wg2[4*j+2], hC, A0);
      A1 = __builtin_elementwise_fma(wg2[4*j+3], hD, A1);
    }
    v2f as = A0 + A1;
    gxp[b][w][l] = as.x + as.y;                // raw partial dot

    asm volatile("s_waitcnt lgkmcnt(0)" ::: "memory");
    __builtin_amdgcn_s_barrier();
    asm volatile("" ::: "memory");

    float p0 = gxp[b][0][l], p1 = gxp[b][1][l];
    float p2 = gxp[b][2][l], p3 = gxp[b][3][l];
    float p4 = gxp[b][4][l], p5 = gxp[b][5][l];
    __builtin_amdgcn_sched_barrier(0);         // gx reads issue before seg reads

    // Fused MLP segment: independent of the recurrence chain -> fills the
    // gx-read + tail latency window.
    if (seg < 6){ runSeg(seg); ++seg; }

    float dr = p0 + p1 + br;
    float du = p2 + p3 + bz;
    float dn = p4 + p5 + bn;
    float r = sigmoidf_(xr + dr);
    float u = sigmoidf_(xz + du);
    float n = tanhf_(fmaf(r, dn, xn));
    h = fmaf(u, h - n, n);
    hbc[w][l] = h;                             // refresh own broadcast buffer

    if ((tl % 6) == w){                        // my turn: snapshot h(tl)
      hsnap[w][l] = h;
      myT = tl; seg = 0;
    }

    // prefetch x for tl+2 into the just-consumed registers
    int tn = tl + 2; if (tn >= tcLen) tn = tcLen - 1;
    const float* xf = xrow + (size_t)tn*G_;
    xr = xf[l]; xz = xf[64+l]; xn = xf[128+l];
  };

  for (int tl = 0; tl < tcLen; tl += 2){       // tcLen is a multiple of 64
    step(xrA, xzA, xnA, tl);
    step(xrB, xzB, xnB, tl+1);
  }

  // Drain pending MLP segments (no barriers needed: wave-private buffers).
  while (seg < 6){ runSeg(seg); ++seg; }

  if (w == 0) hstate[p*H_ + l] = h;
}

extern "C" void kernel_launch(void* const* d_in, const int* in_sizes, int n_in,
                              void* d_out, int out_size, void* d_ws, size_t ws_size,
                              hipStream_t stream)
{
  const float* z    = (const float*)d_in[0];
  const float* w_ih = (const float*)d_in[1];
  const float* w_hh = (const float*)d_in[2];
  const float* b_ih = (const float*)d_in[3];
  const float* b_hh = (const float*)d_in[4];
  const float* w1 = (const float*)d_in[5];
  const float* b1 = (const float*)d_in[6];
  const float* w2 = (const float*)d_in[7];
  const float* b2 = (const float*)d_in[8];
  const float* w3 = (const float*)d_in[9];
  const float* b3 = (const float*)d_in[10];
  const float* w4 = (const float*)d_in[11];
  const float* b4 = (const float*)d_in[12];
  float* out = (float*)d_out;

  const size_t stBytes = (size_t)P_*H_*sizeof(float);
  int tc = 64;
  for (int cand = T_; cand >= 64; cand >>= 1){
    size_t need = (size_t)P_*cand*G_*sizeof(float) + stBytes;
    if (need <= ws_size){ tc = cand; break; }
  }
  float* xpw    = (float*)d_ws;
  float* hstate = (float*)((char*)d_ws + (size_t)P_*tc*G_*sizeof(float));

  for (int t0 = 0; t0 < T_; t0 += tc){
    xproj_kernel<<<dim3(tc/64, P_), 256, 0, stream>>>(z, w_ih, b_ih, xpw, t0, tc);
    gru_kernel<<<dim3(P_), 384, 0, stream>>>(xpw, w_hh, b_hh,
        w1,b1, w2,b2, w3,b3, w4,b4, out, hstate, t0, tc);
  }
}